// Round 2
// baseline (6282.578 us; speedup 1.0000x reference)
//
#include <hip/hip_runtime.h>
#include <stdint.h>
#include <stddef.h>

#define NROWS 65536
#define BM 128
#define NBLK (NROWS / BM)

typedef __attribute__((ext_vector_type(8))) short bf16x8;
typedef __attribute__((ext_vector_type(4))) float f32x4;

struct KeyArr { unsigned k0[32]; unsigned k1[32]; };

// ---------- helpers ----------
__device__ __forceinline__ unsigned short f2bf(float f) {
  unsigned u = __float_as_uint(f);
  u += 0x7fffu + ((u >> 16) & 1u);          // RNE to bf16
  return (unsigned short)(u >> 16);
}

// XOR-swizzled LDS index for [128][256] bf16 tiles (ushort units).
// byte ^= ((row&7)<<4)  ->  ushort col ^= ((row&7)<<3). Conflict-free b128 reads.
__device__ __forceinline__ int hidx(int row, int col) {
  return row * 256 + (col ^ ((row & 7) << 3));
}

// Exact JAX noise, threefry_partitionable=True (JAX >= 0.4.36 default):
//   per-element counter (hi,lo) = (0, idx); bits = out0 ^ out1;
//   XLA uniform bit-trick; sqrt(2) * ErfInv32 (Giles polynomial).
__device__ __attribute__((noinline)) float noise_normal(unsigned k0, unsigned k1, unsigned idx) {
  unsigned x0 = 0u, x1 = idx;
  unsigned ks2 = k0 ^ k1 ^ 0x1BD11BDAu;
  x0 += k0; x1 += k1;
#define TFR(r) { x0 += x1; x1 = (x1 << r) | (x1 >> (32 - r)); x1 ^= x0; }
  TFR(13) TFR(15) TFR(26) TFR(6)
  x0 += k1;  x1 += ks2 + 1u;
  TFR(17) TFR(29) TFR(16) TFR(24)
  x0 += ks2; x1 += k0 + 2u;
  TFR(13) TFR(15) TFR(26) TFR(6)
  x0 += k0;  x1 += k1 + 3u;
  TFR(17) TFR(29) TFR(16) TFR(24)
  x0 += k1;  x1 += ks2 + 4u;
  TFR(13) TFR(15) TFR(26) TFR(6)
  x0 += ks2; x1 += k0 + 5u;
#undef TFR
  unsigned bits = x0 ^ x1;                   // partitionable 32-bit fold
  float f = __uint_as_float((bits >> 9) | 0x3f800000u) - 1.0f;   // [0,1)
  const float mn = -0.99999994f;                                  // nextafter(-1,0)
  float u = f * 2.0f + mn;                                        // (hi-lo) rounds to 2.0f
  u = fmaxf(mn, u);
  float w = -log1pf(-u * u);
  float p;
  if (w < 5.0f) {
    w -= 2.5f;
    p = 2.81022636e-08f;
    p = fmaf(p, w, 3.43273939e-07f);
    p = fmaf(p, w, -3.5233877e-06f);
    p = fmaf(p, w, -4.39150654e-06f);
    p = fmaf(p, w, 0.00021858087f);
    p = fmaf(p, w, -0.00125372503f);
    p = fmaf(p, w, -0.00417768164f);
    p = fmaf(p, w, 0.246640727f);
    p = fmaf(p, w, 1.50140941f);
  } else {
    w = sqrtf(w) - 3.0f;
    p = -0.000200214257f;
    p = fmaf(p, w, 0.000100950558f);
    p = fmaf(p, w, 0.00134934322f);
    p = fmaf(p, w, -0.00367342844f);
    p = fmaf(p, w, 0.00573950773f);
    p = fmaf(p, w, -0.0076224613f);
    p = fmaf(p, w, 0.00943887047f);
    p = fmaf(p, w, 1.00167406f);
    p = fmaf(p, w, 2.83297682f);
  }
  return 1.41421356f * (p * u);
}

// ---------- init kernels ----------
// wbuf (bf16): w1xT[256][64] @0 | w1cT[256][256] @16384 | w2T @81920 | w3T @147456 | w4T[64][256] @212992
__global__ void pack_w_k(const float* __restrict__ W1, const float* __restrict__ W2,
                         const float* __restrict__ W3, const float* __restrict__ W4,
                         unsigned short* __restrict__ wbuf) {
  int idx = blockIdx.x * 256 + threadIdx.x;
  if (idx < 16384)        { int n = idx >> 6, k = idx & 63;                wbuf[idx] = f2bf(W1[k * 256 + n]); }
  else if (idx < 81920)   { int r = idx - 16384;  int n = r >> 8, k = r & 255; wbuf[idx] = f2bf(W1[(96 + k) * 256 + n]); }
  else if (idx < 147456)  { int r = idx - 81920;  int n = r >> 8, k = r & 255; wbuf[idx] = f2bf(W2[k * 256 + n]); }
  else if (idx < 212992)  { int r = idx - 147456; int n = r >> 8, k = r & 255; wbuf[idx] = f2bf(W3[k * 256 + n]); }
  else                    { int r = idx - 212992; int n = r >> 8, k = r & 255; wbuf[idx] = f2bf(W4[k * 64 + n]); }
}

// b1eff[t][n] = b1[n] + sum_j temb(t)[j] * W1[64+j][n]   (t_emb folded into bias)
__global__ void b1eff_k(const float* __restrict__ W1, const float* __restrict__ b1,
                        float* __restrict__ b1eff) {
  int t = blockIdx.x, n = threadIdx.x;
  float acc = b1[n];
#pragma unroll
  for (int j = 0; j < 16; ++j) {
    float arg = (float)t * expf((float)j * (6.907755278982137f / 15.0f));  // exp(linspace(0,ln1000,16))
    acc += sinf(arg) * W1[(64 + j) * 256 + n] + cosf(arg) * W1[(80 + j) * 256 + n];
  }
  b1eff[t * 256 + n] = acc;
}

__global__ void pack_cond_k(const float* __restrict__ src, unsigned short* __restrict__ dst) {
  size_t i = (size_t)(blockIdx.x * 256 + threadIdx.x) * 8;
  float4 a = *(const float4*)(src + i);
  float4 b = *(const float4*)(src + i + 4);
  bf16x8 o;
  o[0] = (short)f2bf(a.x); o[1] = (short)f2bf(a.y); o[2] = (short)f2bf(a.z); o[3] = (short)f2bf(a.w);
  o[4] = (short)f2bf(b.x); o[5] = (short)f2bf(b.y); o[6] = (short)f2bf(b.z); o[7] = (short)f2bf(b.w);
  *(bf16x8*)(dst + i) = o;
}

// ---------- dense 256->256 layer: src(LDS) @ wT(global bf16) + bias -> silu -> dst(LDS) ----------
__device__ __forceinline__ void dense256(const unsigned short* __restrict__ src,
                                         const unsigned short* __restrict__ wT,
                                         const float* __restrict__ bias,
                                         unsigned short* __restrict__ dst,
                                         int ncol0, int l15, int l4) {
  f32x4 zero4 = {0.f, 0.f, 0.f, 0.f};
  f32x4 acc[2][8];
#pragma unroll
  for (int nf = 0; nf < 2; ++nf)
#pragma unroll
    for (int m = 0; m < 8; ++m) acc[nf][m] = zero4;
#pragma unroll
  for (int ks = 0; ks < 8; ++ks) {
    int k0 = ks * 32 + l4 * 8;
    bf16x8 aF[8];
#pragma unroll
    for (int m = 0; m < 8; ++m)
      aF[m] = *(const bf16x8*)&src[hidx(m * 16 + l15, k0)];
#pragma unroll
    for (int nf = 0; nf < 2; ++nf) {
      bf16x8 bF = *(const bf16x8*)&wT[(ncol0 + nf * 16 + l15) * 256 + k0];
#pragma unroll
      for (int m = 0; m < 8; ++m)
        acc[nf][m] = __builtin_amdgcn_mfma_f32_16x16x32_bf16(aF[m], bF, acc[nf][m], 0, 0, 0);
    }
  }
#pragma unroll
  for (int nf = 0; nf < 2; ++nf) {
    float bv = bias[ncol0 + nf * 16 + l15];
#pragma unroll
    for (int m = 0; m < 8; ++m) {
#pragma unroll
      for (int j = 0; j < 4; ++j) {
        float v = acc[nf][m][j] + bv;
        float s = v / (1.0f + __expf(-v));
        dst[hidx(m * 16 + l4 * 4 + j, ncol0 + nf * 16 + l15)] = f2bf(s);
      }
    }
  }
}

// ---------- main persistent kernel: all 32 diffusion steps for a 128-row tile ----------
template <bool CB>
__global__ __launch_bounds__(512, 2) void diff_main(
    const float* __restrict__ cond, const unsigned short* __restrict__ condbf,
    const float* __restrict__ x_init,
    const float* __restrict__ b2, const float* __restrict__ b3, const float* __restrict__ b4,
    const unsigned short* __restrict__ wbuf, const float* __restrict__ b1eff,
    float* __restrict__ out, KeyArr keys) {
  extern __shared__ unsigned short smem[];
  unsigned short* hA = smem;              // [128][256] bf16, swizzled
  unsigned short* hB = smem + 32768;      // [128][256] bf16, swizzled; x_t aliased in cols 0..63
  unsigned short* slot0 = smem + 65536;   // [128][32] bf16 cond staging, stride 56
  unsigned short* slot1 = slot0 + 7168;

  const unsigned short* w1xT = wbuf;
  const unsigned short* w1cT = wbuf + 16384;
  const unsigned short* w2T  = wbuf + 81920;
  const unsigned short* w3T  = wbuf + 147456;
  const unsigned short* w4T  = wbuf + 212992;

  const int tid = threadIdx.x;
  const int wave = tid >> 6, lane = tid & 63;
  const int l15 = lane & 15, l4 = lane >> 4;
  const int ncol0 = wave * 32;            // 32-col slice for 256-wide layers
  const int nf4 = wave & 3, mb4 = (wave >> 2) << 2;  // layer-4 split
  const int row0 = blockIdx.x * BM;
  const int c4 = nf4 * 16 + l15;
  const int srow = tid >> 2, skg = tid & 3;  // cond staging mapping

  f32x4 zero4 = {0.f, 0.f, 0.f, 0.f};

  // x fp32 master in registers (layer-4 C-fragment layout) + bf16 copy into hB (xseg)
  float x[4][4];
#pragma unroll
  for (int m = 0; m < 4; ++m)
#pragma unroll
    for (int j = 0; j < 4; ++j) {
      int rl = (mb4 + m) * 16 + l4 * 4 + j;
      x[m][j] = x_init[(size_t)(row0 + rl) * 64 + c4];
      hB[hidx(rl, c4)] = f2bf(x[m][j]);
    }
  __syncthreads();

  float4 sa, sb; bf16x8 sv;
#define STAGE_LOAD(KC) do { \
    if (CB) { sv = *(const bf16x8*)&condbf[(size_t)(row0 + srow) * 256 + (KC) * 32 + skg * 8]; } \
    else { const float* p_ = &cond[(size_t)(row0 + srow) * 256 + (KC) * 32 + skg * 8]; \
           sa = *(const float4*)p_; sb = *(const float4*)(p_ + 4); } \
  } while (0)
#define STAGE_WRITE(DST) do { \
    bf16x8 v_; \
    if (CB) v_ = sv; \
    else { v_[0]=(short)f2bf(sa.x); v_[1]=(short)f2bf(sa.y); v_[2]=(short)f2bf(sa.z); v_[3]=(short)f2bf(sa.w); \
           v_[4]=(short)f2bf(sb.x); v_[5]=(short)f2bf(sb.y); v_[6]=(short)f2bf(sb.z); v_[7]=(short)f2bf(sb.w); } \
    *(bf16x8*)&(DST)[srow * 56 + skg * 8] = v_; \
  } while (0)

#pragma unroll 1
  for (int t = 31; t >= 0; --t) {
    // schedule constants (match jnp.linspace + f32 cumprod order)
    const float bstep = (0.01f - 0.0001f) / 31.0f;
    float beta_t = 0.0001f + bstep * (float)t;
    float alpha_t = 1.0f - beta_t;
    float abar = 1.0f;
    for (int i = 0; i <= t; ++i) abar *= (1.0f - (0.0001f + bstep * (float)i));

    // ---- Layer 1: [x_t | cond] @ W1 + b1eff(t) -> silu -> hA ----
    f32x4 acc[2][8];
#pragma unroll
    for (int nf = 0; nf < 2; ++nf)
#pragma unroll
      for (int m = 0; m < 8; ++m) acc[nf][m] = zero4;

    STAGE_LOAD(0);
    // x part, K=64 (A from hB/xseg)
#pragma unroll
    for (int ks = 0; ks < 2; ++ks) {
      int k0 = ks * 32 + l4 * 8;
      bf16x8 aF[8];
#pragma unroll
      for (int m = 0; m < 8; ++m) aF[m] = *(const bf16x8*)&hB[hidx(m * 16 + l15, k0)];
#pragma unroll
      for (int nf = 0; nf < 2; ++nf) {
        bf16x8 bF = *(const bf16x8*)&w1xT[(ncol0 + nf * 16 + l15) * 64 + k0];
#pragma unroll
        for (int m = 0; m < 8; ++m)
          acc[nf][m] = __builtin_amdgcn_mfma_f32_16x16x32_bf16(aF[m], bF, acc[nf][m], 0, 0, 0);
      }
    }
    STAGE_WRITE(slot0);
    __syncthreads();

    // cond part, K=256, double-buffered LDS staging
#pragma unroll 1
    for (int kc = 0; kc < 8; ++kc) {
      unsigned short* cur = (kc & 1) ? slot1 : slot0;
      unsigned short* nxt = (kc & 1) ? slot0 : slot1;
      if (kc < 7) STAGE_LOAD(kc + 1);
      bf16x8 aF[8];
#pragma unroll
      for (int m = 0; m < 8; ++m)
        aF[m] = *(const bf16x8*)&cur[(m * 16 + l15) * 56 + l4 * 8];
#pragma unroll
      for (int nf = 0; nf < 2; ++nf) {
        bf16x8 bF = *(const bf16x8*)&w1cT[(ncol0 + nf * 16 + l15) * 256 + kc * 32 + l4 * 8];
#pragma unroll
        for (int m = 0; m < 8; ++m)
          acc[nf][m] = __builtin_amdgcn_mfma_f32_16x16x32_bf16(aF[m], bF, acc[nf][m], 0, 0, 0);
      }
      if (kc < 7) { STAGE_WRITE(nxt); __syncthreads(); }
    }
    // bias + silu -> hA
#pragma unroll
    for (int nf = 0; nf < 2; ++nf) {
      float bv = b1eff[t * 256 + ncol0 + nf * 16 + l15];
#pragma unroll
      for (int m = 0; m < 8; ++m) {
#pragma unroll
        for (int j = 0; j < 4; ++j) {
          float v = acc[nf][m][j] + bv;
          float s = v / (1.0f + __expf(-v));
          hA[hidx(m * 16 + l4 * 4 + j, ncol0 + nf * 16 + l15)] = f2bf(s);
        }
      }
    }
    __syncthreads();

    dense256(hA, w2T, b2, hB, ncol0, l15, l4);   // h1 -> h2
    __syncthreads();
    dense256(hB, w3T, b3, hA, ncol0, l15, l4);   // h2 -> h3
    __syncthreads();

    // ---- Layer 4: h3 @ W4 + b4 -> eps (regs) ----
    f32x4 a4[4];
#pragma unroll
    for (int m = 0; m < 4; ++m) a4[m] = zero4;
#pragma unroll
    for (int ks = 0; ks < 8; ++ks) {
      int k0 = ks * 32 + l4 * 8;
      bf16x8 bF = *(const bf16x8*)&w4T[c4 * 256 + k0];
#pragma unroll
      for (int m = 0; m < 4; ++m) {
        bf16x8 aF = *(const bf16x8*)&hA[hidx((mb4 + m) * 16 + l15, k0)];
        a4[m] = __builtin_amdgcn_mfma_f32_16x16x32_bf16(aF, bF, a4[m], 0, 0, 0);
      }
    }

    // ---- diffusion update ----
    float b4v = b4[c4];
    float sqab = sqrtf(abar), s1 = sqrtf(1.0f - abar);
    float sqa = sqrtf(alpha_t), sqb = sqrtf(beta_t);
    unsigned kk0 = keys.k0[31 - t], kk1 = keys.k1[31 - t];
#pragma unroll
    for (int m = 0; m < 4; ++m) {
#pragma unroll
      for (int j = 0; j < 4; ++j) {
        float eps = a4[m][j] + b4v;
        int rl = (mb4 + m) * 16 + l4 * 4 + j;
        float x0p = (x[m][j] - s1 * eps) / sqab;
        if (t > 0) {
          float z = noise_normal(kk0, kk1, (unsigned)((row0 + rl) * 64 + c4));
          x[m][j] = sqa * x0p + sqb * z;
        } else {
          x[m][j] = x0p;
        }
      }
    }
    if (t > 0) {
#pragma unroll
      for (int m = 0; m < 4; ++m)
#pragma unroll
        for (int j = 0; j < 4; ++j) {
          int rl = (mb4 + m) * 16 + l4 * 4 + j;
          hB[hidx(rl, c4)] = f2bf(x[m][j]);     // new x_t -> xseg (hB alias; h2 is dead)
        }
    } else {
#pragma unroll
      for (int m = 0; m < 4; ++m)
#pragma unroll
        for (int j = 0; j < 4; ++j) {
          int rl = (mb4 + m) * 16 + l4 * 4 + j;
          out[(size_t)(row0 + rl) * 64 + c4] = x[m][j];
        }
    }
    __syncthreads();
  }
#undef STAGE_LOAD
#undef STAGE_WRITE
}

// ---------- host ----------
static void host_threefry(unsigned k0, unsigned k1, unsigned x0, unsigned x1,
                          unsigned* o0, unsigned* o1) {
  unsigned ks2 = k0 ^ k1 ^ 0x1BD11BDAu;
  x0 += k0; x1 += k1;
#define HR(r) { x0 += x1; x1 = (x1 << r) | (x1 >> (32 - r)); x1 ^= x0; }
  HR(13) HR(15) HR(26) HR(6)
  x0 += k1;  x1 += ks2 + 1u;
  HR(17) HR(29) HR(16) HR(24)
  x0 += ks2; x1 += k0 + 2u;
  HR(13) HR(15) HR(26) HR(6)
  x0 += k0;  x1 += k1 + 3u;
  HR(17) HR(29) HR(16) HR(24)
  x0 += k1;  x1 += ks2 + 4u;
  HR(13) HR(15) HR(26) HR(6)
  x0 += ks2; x1 += k0 + 5u;
#undef HR
  *o0 = x0; *o1 = x1;
}

extern "C" void kernel_launch(void* const* d_in, const int* in_sizes, int n_in,
                              void* d_out, int out_size, void* d_ws, size_t ws_size,
                              hipStream_t stream) {
  const float* cond   = (const float*)d_in[0];
  const float* x_init = (const float*)d_in[1];
  const float* W1 = (const float*)d_in[2];
  const float* b1 = (const float*)d_in[3];
  const float* W2 = (const float*)d_in[4];
  const float* b2 = (const float*)d_in[5];
  const float* W3 = (const float*)d_in[6];
  const float* b3 = (const float*)d_in[7];
  const float* W4 = (const float*)d_in[8];
  const float* b4 = (const float*)d_in[9];

  unsigned short* wbuf = (unsigned short*)d_ws;                    // 458752 B
  float* b1eff = (float*)((char*)d_ws + 458752);                   // 32768 B
  const size_t condoff = 491520;
  bool use_cb = ws_size >= condoff + (size_t)NROWS * 256 * 2;
  unsigned short* condbf = use_cb ? (unsigned short*)((char*)d_ws + condoff) : nullptr;

  pack_w_k<<<896, 256, 0, stream>>>(W1, W2, W3, W4, wbuf);
  b1eff_k<<<32, 256, 0, stream>>>(W1, b1, b1eff);
  if (use_cb) pack_cond_k<<<8192, 256, 0, stream>>>(cond, condbf);

  // jax.random.split(jax.random.key(42), 32), threefry_partitionable=True:
  // key_i = threefry2x32((0,42), (hi,lo)=(0,i)) -> (out0, out1)
  KeyArr keys;
  for (int i = 0; i < 32; ++i) {
    unsigned o0, o1;
    host_threefry(0u, 42u, 0u, (unsigned)i, &o0, &o1);
    keys.k0[i] = o0; keys.k1[i] = o1;
  }

  const int shmem = 159744;  // 2*64KB h-buffers + 2*14KB cond slots
  if (use_cb) {
    hipFuncSetAttribute((const void*)diff_main<true>, hipFuncAttributeMaxDynamicSharedMemorySize, 160 * 1024);
    diff_main<true><<<NBLK, 512, shmem, stream>>>(cond, condbf, x_init, b2, b3, b4,
                                                  wbuf, b1eff, (float*)d_out, keys);
  } else {
    hipFuncSetAttribute((const void*)diff_main<false>, hipFuncAttributeMaxDynamicSharedMemorySize, 160 * 1024);
    diff_main<false><<<NBLK, 512, shmem, stream>>>(cond, nullptr, x_init, b2, b3, b4,
                                                   wbuf, b1eff, (float*)d_out, keys);
  }
}

// Round 3
// 3498.573 us; speedup vs baseline: 1.7958x; 1.7958x over previous
//
#include <hip/hip_runtime.h>
#include <stdint.h>
#include <stddef.h>

#define NROWS 65536
#define BM 128
#define NBLK (NROWS / BM)

typedef __attribute__((ext_vector_type(8))) short bf16x8;
typedef __attribute__((ext_vector_type(4))) float f32x4;

struct KeyArr { unsigned k0[32]; unsigned k1[32]; };

// ---------- helpers ----------
__device__ __forceinline__ unsigned short f2bf(float f) {
  unsigned u = __float_as_uint(f);
  u += 0x7fffu + ((u >> 16) & 1u);          // RNE to bf16
  return (unsigned short)(u >> 16);
}

__device__ __forceinline__ unsigned cvtpk(float lo, float hi) {
  unsigned r;
  asm("v_cvt_pk_bf16_f32 %0, %1, %2" : "=v"(r) : "v"(lo), "v"(hi));
  return r;
}

__device__ __forceinline__ float silu(float v) {
  return v / (1.0f + __expf(-v));
}

__device__ __forceinline__ void gload_lds16(const void* g, void* l) {
  __builtin_amdgcn_global_load_lds(
      (const __attribute__((address_space(1))) unsigned int*)g,
      (__attribute__((address_space(3))) unsigned int*)l, 16, 0, 0);
}

// Exact JAX noise, threefry_partitionable (verified round 2).
__device__ __attribute__((noinline)) float noise_normal(unsigned k0, unsigned k1, unsigned idx) {
  unsigned x0 = 0u, x1 = idx;
  unsigned ks2 = k0 ^ k1 ^ 0x1BD11BDAu;
  x0 += k0; x1 += k1;
#define TFR(r) { x0 += x1; x1 = (x1 << r) | (x1 >> (32 - r)); x1 ^= x0; }
  TFR(13) TFR(15) TFR(26) TFR(6)
  x0 += k1;  x1 += ks2 + 1u;
  TFR(17) TFR(29) TFR(16) TFR(24)
  x0 += ks2; x1 += k0 + 2u;
  TFR(13) TFR(15) TFR(26) TFR(6)
  x0 += k0;  x1 += k1 + 3u;
  TFR(17) TFR(29) TFR(16) TFR(24)
  x0 += k1;  x1 += ks2 + 4u;
  TFR(13) TFR(15) TFR(26) TFR(6)
  x0 += ks2; x1 += k0 + 5u;
#undef TFR
  unsigned bits = x0 ^ x1;
  float f = __uint_as_float((bits >> 9) | 0x3f800000u) - 1.0f;
  const float mn = -0.99999994f;
  float u = f * 2.0f + mn;
  u = fmaxf(mn, u);
  float w = -log1pf(-u * u);
  float p;
  if (w < 5.0f) {
    w -= 2.5f;
    p = 2.81022636e-08f;
    p = fmaf(p, w, 3.43273939e-07f);
    p = fmaf(p, w, -3.5233877e-06f);
    p = fmaf(p, w, -4.39150654e-06f);
    p = fmaf(p, w, 0.00021858087f);
    p = fmaf(p, w, -0.00125372503f);
    p = fmaf(p, w, -0.00417768164f);
    p = fmaf(p, w, 0.246640727f);
    p = fmaf(p, w, 1.50140941f);
  } else {
    w = sqrtf(w) - 3.0f;
    p = -0.000200214257f;
    p = fmaf(p, w, 0.000100950558f);
    p = fmaf(p, w, 0.00134934322f);
    p = fmaf(p, w, -0.00367342844f);
    p = fmaf(p, w, 0.00573950773f);
    p = fmaf(p, w, -0.0076224613f);
    p = fmaf(p, w, 0.00943887047f);
    p = fmaf(p, w, 1.00167406f);
    p = fmaf(p, w, 2.83297682f);
  }
  return 1.41421356f * (p * u);
}

// ---------- init kernels ----------
// ws: weight frags (bf16, frag-major, 448 frags x 1 KB) @0 ; b1eff f32 @458752
// frag g, lane l (l15=l&15, l4=l>>4), elem e: A[row=n=16t+l15][k=32T+8*l4+e] = W[k][n]
__global__ void pack_w_k(const float* __restrict__ W1, const float* __restrict__ W2,
                         const float* __restrict__ W3, const float* __restrict__ W4,
                         unsigned short* __restrict__ wbuf) {
  int o = blockIdx.x * 256 + threadIdx.x;     // 896 blocks -> 229376 ushorts
  int g = o >> 9, q = o & 511, lane = q >> 3, e = q & 7;
  int l15 = lane & 15, kl = (lane >> 4) * 8 + e;
  float v;
  if (g < 32)       { int T = g >> 4,        t = g & 15;        v = W1[(32*T + kl) * 256 + 16*t + l15]; }
  else if (g < 160) { int G = g-32,  T = G >> 4, t = G & 15;    v = W1[(96 + 32*T + kl) * 256 + 16*t + l15]; }
  else if (g < 288) { int G = g-160, T = G >> 4, t = G & 15;    v = W2[(32*T + kl) * 256 + 16*t + l15]; }
  else if (g < 416) { int G = g-288, T = G >> 4, t = G & 15;    v = W3[(32*T + kl) * 256 + 16*t + l15]; }
  else              { int G = g-416, T = G >> 2, t = G & 3;     v = W4[(32*T + kl) * 64 + 16*t + l15]; }
  wbuf[o] = f2bf(v);
}

// b1eff[t][n] = b1[n] + sum_j temb(t)[j] * W1[64+j][n]
__global__ void b1eff_k(const float* __restrict__ W1, const float* __restrict__ b1,
                        float* __restrict__ b1eff) {
  int t = blockIdx.x, n = threadIdx.x;
  float acc = b1[n];
#pragma unroll
  for (int j = 0; j < 16; ++j) {
    float arg = (float)t * expf((float)j * (6.907755278982137f / 15.0f));
    acc += sinf(arg) * W1[(64 + j) * 256 + n] + cosf(arg) * W1[(80 + j) * 256 + n];
  }
  b1eff[t * 256 + n] = acc;
}

// ---------- weight-chunk staging ----------
// chunk c of step: 64 frags (64 KB). double-buffered in LDS. b1eff staged with chunk 0.
__device__ __forceinline__ void issue_chunk(const unsigned short* __restrict__ wsW,
                                            const float* __restrict__ b1eff,
                                            unsigned short* smem, int k,
                                            int wave, int lane) {
  int c = k % 7;
  unsigned short* dst = smem + ((k & 1) << 15);
  const unsigned short* src = wsW + c * 32768;
#pragma unroll
  for (int rr = 0; rr < 8; ++rr) {
    int f = rr * 8 + wave;
    gload_lds16(src + f * 512 + lane * 8, dst + f * 512 + lane * 8);
  }
  if (wave == 0 && c == 0) {
    int t = 31 - k / 7;
    if (t >= 0) {
      float* biasF = (float*)(smem + 73728);
      gload_lds16(b1eff + t * 256 + lane * 4, biasF + lane * 4);
    }
  }
}

#define MF(W, B, C) __builtin_amdgcn_mfma_f32_16x16x32_bf16((W), (B), (C), 0, 0, 0)

// ---------- main persistent kernel ----------
__global__ __launch_bounds__(512, 2) void diff_main(
    const float* __restrict__ cond, const float* __restrict__ x_init,
    const float* __restrict__ b2g, const float* __restrict__ b3g, const float* __restrict__ b4g,
    const unsigned short* __restrict__ wsW, const float* __restrict__ b1eff,
    float* __restrict__ out, KeyArr keys) {
  extern __shared__ unsigned short smem[];
  unsigned short* scratch = smem + 65536;          // byte 131072: 8 waves x 2 KB
  float* biasF = (float*)(smem + 73728);           // byte 147456: [b1eff_t 256][b2 256][b3 256][b4 64]

  const int tid = threadIdx.x;
  const int wave = tid >> 6, lane = tid & 63;
  const int l15 = lane & 15, l4 = lane >> 4;
  const int lane8 = lane * 8;
  const int row = blockIdx.x * BM + wave * 16 + l15;   // this lane's row r

  // stage b2/b3/b4 -> LDS
  for (int i = tid; i < 576; i += 512) {
    float v = (i < 256) ? b2g[i] : (i < 512) ? b3g[i - 256] : b4g[i - 512];
    biasF[256 + i] = v;
  }

  // x master (f32) in C-fragment layout: x[tt][j] = x[r=row][c=16tt+4*l4+j]
  float x[4][4];
#pragma unroll
  for (int tt = 0; tt < 4; ++tt) {
    float4 xv = *(const float4*)(x_init + (size_t)row * 64 + 16 * tt + 4 * l4);
    x[tt][0] = xv.x; x[tt][1] = xv.y; x[tt][2] = xv.z; x[tt][3] = xv.w;
  }

  // cond B-frags, register-resident: cf[T] = cond[r=row][k=32T+8*l4+e]
  bf16x8 cf[8];
#pragma unroll
  for (int T = 0; T < 8; ++T) {
    const float* p = cond + (size_t)row * 256 + 32 * T + 8 * l4;
    float4 a = *(const float4*)p;
    float4 b = *(const float4*)(p + 4);
    union { bf16x8 v; unsigned u[4]; } cu;
    cu.u[0] = cvtpk(a.x, a.y); cu.u[1] = cvtpk(a.z, a.w);
    cu.u[2] = cvtpk(b.x, b.y); cu.u[3] = cvtpk(b.z, b.w);
    cf[T] = cu.v;
  }

  // wave-private scratch transpose: acc layout -> B-frags (16 r x 32 k, XOR slot swizzle)
  unsigned short* scr0 = scratch + wave * 1024;
  bf16x8 xf[2];
#define XTRANS() do { \
  _Pragma("unroll") for (int T_ = 0; T_ < 2; ++T_) { \
    unsigned short* scrT = scr0 + (T_ & 1) * 512; \
    _Pragma("unroll") for (int p_ = 0; p_ < 2; ++p_) { \
      int tt_ = 2 * T_ + p_; \
      uint2 wv_; wv_.x = cvtpk(x[tt_][0], x[tt_][1]); wv_.y = cvtpk(x[tt_][2], x[tt_][3]); \
      *(uint2*)(scrT + l15 * 32 + (((p_ << 2) | l4) ^ (l15 & 6)) * 4) = wv_; \
    } \
    xf[T_] = *(const bf16x8*)(scrT + l15 * 32 + (((l4 << 1) ^ (l15 & 6)) * 4)); \
  } \
} while (0)

  XTRANS();

  int ck = 0;
  const unsigned short* bufp = smem;
  issue_chunk(wsW, b1eff, smem, 0, wave, lane);
  __syncthreads();                                   // chunk0 (+b1eff[31]) resident
  issue_chunk(wsW, b1eff, smem, 1, wave, lane);

  f32x4 acc[16];
  const f32x4 zero4 = {0.f, 0.f, 0.f, 0.f};
  bf16x8 hf[8];

#define WFRAG(f) (*(const bf16x8*)(bufp + (f) * 512 + lane8))
#define SEG16(FBASE, HFR) { bf16x8 b_ = (HFR); \
  _Pragma("unroll") for (int tt_ = 0; tt_ < 16; ++tt_) \
    acc[tt_] = MF(WFRAG((FBASE) + tt_), b_, acc[tt_]); }
#define SEG4(FBASE, HFR) { bf16x8 b_ = (HFR); \
  _Pragma("unroll") for (int tt_ = 0; tt_ < 4; ++tt_) \
    acc[tt_] = MF(WFRAG((FBASE) + tt_), b_, acc[tt_]); }
#define NEXTCHUNK() do { __syncthreads(); ++ck; bufp = smem + ((ck & 1) << 15); \
  issue_chunk(wsW, b1eff, smem, ck + 1, wave, lane); } while (0)
#define ACT(BOFF) do { \
  _Pragma("unroll") for (int T_ = 0; T_ < 8; ++T_) { \
    unsigned short* scrT = scr0 + (T_ & 1) * 512; \
    _Pragma("unroll") for (int p_ = 0; p_ < 2; ++p_) { \
      int tt_ = 2 * T_ + p_; \
      float4 bv = *(const float4*)(biasF + (BOFF) + tt_ * 16 + l4 * 4); \
      float s0 = silu(acc[tt_][0] + bv.x), s1 = silu(acc[tt_][1] + bv.y); \
      float s2 = silu(acc[tt_][2] + bv.z), s3 = silu(acc[tt_][3] + bv.w); \
      uint2 wv_; wv_.x = cvtpk(s0, s1); wv_.y = cvtpk(s2, s3); \
      *(uint2*)(scrT + l15 * 32 + (((p_ << 2) | l4) ^ (l15 & 6)) * 4) = wv_; \
    } \
    hf[T_] = *(const bf16x8*)(scrT + l15 * 32 + (((l4 << 1) ^ (l15 & 6)) * 4)); \
  } \
} while (0)
#define ZACC(N) { _Pragma("unroll") for (int z_ = 0; z_ < (N); ++z_) acc[z_] = zero4; }

#pragma unroll 1
  for (int t = 31; t >= 0; --t) {
    const float bstep = (0.01f - 0.0001f) / 31.0f;
    float beta_t = 0.0001f + bstep * (float)t;
    float alpha_t = 1.0f - beta_t;
    float abar = 1.0f;
    for (int i = 0; i <= t; ++i) abar *= (1.0f - (0.0001f + bstep * (float)i));

    ZACC(16);
    // chunk0: L1x T0,T1 + L1c T0,T1
    SEG16(0, xf[0]); SEG16(16, xf[1]); SEG16(32, cf[0]); SEG16(48, cf[1]);
    NEXTCHUNK();
    // chunk1: L1c T2..T5
    SEG16(0, cf[2]); SEG16(16, cf[3]); SEG16(32, cf[4]); SEG16(48, cf[5]);
    NEXTCHUNK();
    // chunk2: L1c T6,T7 ; h1 = silu(acc + b1eff) ; L2 T0,T1
    SEG16(0, cf[6]); SEG16(16, cf[7]);
    ACT(0);
    ZACC(16);
    SEG16(32, hf[0]); SEG16(48, hf[1]);
    NEXTCHUNK();
    // chunk3: L2 T2..T5
    SEG16(0, hf[2]); SEG16(16, hf[3]); SEG16(32, hf[4]); SEG16(48, hf[5]);
    NEXTCHUNK();
    // chunk4: L2 T6,T7 ; h2 ; L3 T0,T1
    SEG16(0, hf[6]); SEG16(16, hf[7]);
    ACT(256);
    ZACC(16);
    SEG16(32, hf[0]); SEG16(48, hf[1]);
    NEXTCHUNK();
    // chunk5: L3 T2..T5
    SEG16(0, hf[2]); SEG16(16, hf[3]); SEG16(32, hf[4]); SEG16(48, hf[5]);
    NEXTCHUNK();
    // chunk6: L3 T6,T7 ; h3 ; L4 ; diffusion update
    SEG16(0, hf[6]); SEG16(16, hf[7]);
    ACT(512);
    ZACC(4);
#pragma unroll
    for (int T = 0; T < 8; ++T) SEG4(32 + 4 * T, hf[T]);

    float sqab = sqrtf(abar), s1d = sqrtf(1.0f - abar);
    float sqa = sqrtf(alpha_t), sqb = sqrtf(beta_t);
    unsigned kk0 = keys.k0[31 - t], kk1 = keys.k1[31 - t];
#pragma unroll
    for (int tt = 0; tt < 4; ++tt) {
      float4 b4v = *(const float4*)(biasF + 768 + tt * 16 + l4 * 4);
#pragma unroll
      for (int j = 0; j < 4; ++j) {
        float bj = (j == 0) ? b4v.x : (j == 1) ? b4v.y : (j == 2) ? b4v.z : b4v.w;
        float eps = acc[tt][j] + bj;
        float x0p = (x[tt][j] - s1d * eps) / sqab;
        if (t > 0) {
          float z = noise_normal(kk0, kk1, (unsigned)(row * 64 + 16 * tt + 4 * l4 + j));
          x[tt][j] = sqa * x0p + sqb * z;
        } else {
          x[tt][j] = x0p;
        }
      }
    }
    if (t > 0) {
      XTRANS();          // new x_t -> B-frags for next step's L1
    } else {
#pragma unroll
      for (int tt = 0; tt < 4; ++tt) {
        float4 ov; ov.x = x[tt][0]; ov.y = x[tt][1]; ov.z = x[tt][2]; ov.w = x[tt][3];
        *(float4*)(out + (size_t)row * 64 + 16 * tt + 4 * l4) = ov;
      }
    }
    NEXTCHUNK();
  }
}

// ---------- host ----------
static void host_threefry(unsigned k0, unsigned k1, unsigned x0, unsigned x1,
                          unsigned* o0, unsigned* o1) {
  unsigned ks2 = k0 ^ k1 ^ 0x1BD11BDAu;
  x0 += k0; x1 += k1;
#define HR(r) { x0 += x1; x1 = (x1 << r) | (x1 >> (32 - r)); x1 ^= x0; }
  HR(13) HR(15) HR(26) HR(6)
  x0 += k1;  x1 += ks2 + 1u;
  HR(17) HR(29) HR(16) HR(24)
  x0 += ks2; x1 += k0 + 2u;
  HR(13) HR(15) HR(26) HR(6)
  x0 += k0;  x1 += k1 + 3u;
  HR(17) HR(29) HR(16) HR(24)
  x0 += k1;  x1 += ks2 + 4u;
  HR(13) HR(15) HR(26) HR(6)
  x0 += ks2; x1 += k0 + 5u;
#undef HR
  *o0 = x0; *o1 = x1;
}

extern "C" void kernel_launch(void* const* d_in, const int* in_sizes, int n_in,
                              void* d_out, int out_size, void* d_ws, size_t ws_size,
                              hipStream_t stream) {
  const float* cond   = (const float*)d_in[0];
  const float* x_init = (const float*)d_in[1];
  const float* W1 = (const float*)d_in[2];
  const float* b1 = (const float*)d_in[3];
  const float* W2 = (const float*)d_in[4];
  const float* b2 = (const float*)d_in[5];
  const float* W3 = (const float*)d_in[6];
  const float* b3 = (const float*)d_in[7];
  const float* W4 = (const float*)d_in[8];
  const float* b4 = (const float*)d_in[9];

  unsigned short* wbuf = (unsigned short*)d_ws;          // 448 KB frag-major weights
  float* b1eff = (float*)((char*)d_ws + 458752);         // 32 KB

  pack_w_k<<<896, 256, 0, stream>>>(W1, W2, W3, W4, wbuf);
  b1eff_k<<<32, 256, 0, stream>>>(W1, b1, b1eff);

  // jax.random.split(jax.random.key(42), 32), threefry_partitionable (verified r2)
  KeyArr keys;
  for (int i = 0; i < 32; ++i) {
    unsigned o0, o1;
    host_threefry(0u, 42u, 0u, (unsigned)i, &o0, &o1);
    keys.k0[i] = o0; keys.k1[i] = o1;
  }

  const int shmem = 150784;   // 2x64KB weight dbuf + 16KB scratch + 2.3KB biases
  hipFuncSetAttribute((const void*)diff_main, hipFuncAttributeMaxDynamicSharedMemorySize, 160 * 1024);
  diff_main<<<NBLK, 512, shmem, stream>>>(cond, x_init, b2, b3, b4,
                                          wbuf, b1eff, (float*)d_out, keys);
}

// Round 4
// 2093.096 us; speedup vs baseline: 3.0016x; 1.6715x over previous
//
#include <hip/hip_runtime.h>
#include <stdint.h>
#include <stddef.h>

#define NROWS 65536
#define BM 128
#define NBLK (NROWS / BM)

typedef __attribute__((ext_vector_type(8))) short bf16x8;
typedef __attribute__((ext_vector_type(4))) float f32x4;

// per-step constants, host-precomputed with the exact f32 op sequence of the reference
struct Consts {
  unsigned k0[32]; unsigned k1[32];
  float sqab[32];   // sqrt(alpha_bar[t])
  float s1d[32];    // sqrt(1 - alpha_bar[t])
  float sqa[32];    // sqrt(alpha[t])
  float sqb[32];    // sqrt(beta[t])
  float inva[32];   // 1 / sqrt(alpha_bar[t])
};

// ---------- helpers ----------
__device__ __forceinline__ unsigned short f2bf(float f) {
  unsigned u = __float_as_uint(f);
  u += 0x7fffu + ((u >> 16) & 1u);          // RNE to bf16
  return (unsigned short)(u >> 16);
}

__device__ __forceinline__ unsigned cvtpk(float lo, float hi) {
  unsigned r;
  asm("v_cvt_pk_bf16_f32 %0, %1, %2" : "=v"(r) : "v"(lo), "v"(hi));
  return r;
}

__device__ __forceinline__ float silu(float v) {
  return v * __builtin_amdgcn_rcpf(1.0f + __expf(-v));
}

__device__ __forceinline__ void gload_lds16(const void* g, void* l) {
  __builtin_amdgcn_global_load_lds(
      (const __attribute__((address_space(1))) unsigned int*)g,
      (__attribute__((address_space(3))) unsigned int*)l, 16, 0, 0);
}

// Exact JAX noise, threefry_partitionable (verified round 2). INLINE — no ABI call.
__device__ __forceinline__ float noise_normal(unsigned k0, unsigned k1, unsigned idx) {
  unsigned x0 = 0u, x1 = idx;
  unsigned ks2 = k0 ^ k1 ^ 0x1BD11BDAu;
  x0 += k0; x1 += k1;
#define TFR(r) { x0 += x1; x1 = (x1 << r) | (x1 >> (32 - r)); x1 ^= x0; }
  TFR(13) TFR(15) TFR(26) TFR(6)
  x0 += k1;  x1 += ks2 + 1u;
  TFR(17) TFR(29) TFR(16) TFR(24)
  x0 += ks2; x1 += k0 + 2u;
  TFR(13) TFR(15) TFR(26) TFR(6)
  x0 += k0;  x1 += k1 + 3u;
  TFR(17) TFR(29) TFR(16) TFR(24)
  x0 += k1;  x1 += ks2 + 4u;
  TFR(13) TFR(15) TFR(26) TFR(6)
  x0 += ks2; x1 += k0 + 5u;
#undef TFR
  unsigned bits = x0 ^ x1;
  float f = __uint_as_float((bits >> 9) | 0x3f800000u) - 1.0f;
  const float mn = -0.99999994f;
  float u = f * 2.0f + mn;
  u = fmaxf(mn, u);
  float w = -__logf(fmaf(-u, u, 1.0f));     // == -log1p(-u*u) to ~1e-6 rel
  float p;
  if (w < 5.0f) {
    w -= 2.5f;
    p = 2.81022636e-08f;
    p = fmaf(p, w, 3.43273939e-07f);
    p = fmaf(p, w, -3.5233877e-06f);
    p = fmaf(p, w, -4.39150654e-06f);
    p = fmaf(p, w, 0.00021858087f);
    p = fmaf(p, w, -0.00125372503f);
    p = fmaf(p, w, -0.00417768164f);
    p = fmaf(p, w, 0.246640727f);
    p = fmaf(p, w, 1.50140941f);
  } else {
    w = sqrtf(w) - 3.0f;
    p = -0.000200214257f;
    p = fmaf(p, w, 0.000100950558f);
    p = fmaf(p, w, 0.00134934322f);
    p = fmaf(p, w, -0.00367342844f);
    p = fmaf(p, w, 0.00573950773f);
    p = fmaf(p, w, -0.0076224613f);
    p = fmaf(p, w, 0.00943887047f);
    p = fmaf(p, w, 1.00167406f);
    p = fmaf(p, w, 2.83297682f);
  }
  return 1.41421356f * (p * u);
}

// ---------- init kernels ----------
// ws: weight frags (bf16, frag-major, 448 frags x 1 KB) @0 ; b1eff f32 @458752
// frag g, lane l (l15=l&15, l4=l>>4), elem e: A[row=n=16t+l15][k=32T+8*l4+e] = W[k][n]
__global__ void pack_w_k(const float* __restrict__ W1, const float* __restrict__ W2,
                         const float* __restrict__ W3, const float* __restrict__ W4,
                         unsigned short* __restrict__ wbuf) {
  int o = blockIdx.x * 256 + threadIdx.x;     // 896 blocks -> 229376 ushorts
  int g = o >> 9, q = o & 511, lane = q >> 3, e = q & 7;
  int l15 = lane & 15, kl = (lane >> 4) * 8 + e;
  float v;
  if (g < 32)       { int T = g >> 4,        t = g & 15;        v = W1[(32*T + kl) * 256 + 16*t + l15]; }
  else if (g < 160) { int G = g-32,  T = G >> 4, t = G & 15;    v = W1[(96 + 32*T + kl) * 256 + 16*t + l15]; }
  else if (g < 288) { int G = g-160, T = G >> 4, t = G & 15;    v = W2[(32*T + kl) * 256 + 16*t + l15]; }
  else if (g < 416) { int G = g-288, T = G >> 4, t = G & 15;    v = W3[(32*T + kl) * 256 + 16*t + l15]; }
  else              { int G = g-416, T = G >> 2, t = G & 3;     v = W4[(32*T + kl) * 64 + 16*t + l15]; }
  wbuf[o] = f2bf(v);
}

// b1eff[t][n] = b1[n] + sum_j temb(t)[j] * W1[64+j][n]
__global__ void b1eff_k(const float* __restrict__ W1, const float* __restrict__ b1,
                        float* __restrict__ b1eff) {
  int t = blockIdx.x, n = threadIdx.x;
  float acc = b1[n];
#pragma unroll
  for (int j = 0; j < 16; ++j) {
    float arg = (float)t * expf((float)j * (6.907755278982137f / 15.0f));
    acc += sinf(arg) * W1[(64 + j) * 256 + n] + cosf(arg) * W1[(80 + j) * 256 + n];
  }
  b1eff[t * 256 + n] = acc;
}

// ---------- weight-chunk staging ----------
// chunk c of step: 64 frags (64 KB). double-buffered in LDS. b1eff staged with chunk 0.
__device__ __forceinline__ void issue_chunk(const unsigned short* __restrict__ wsW,
                                            const float* __restrict__ b1eff,
                                            unsigned short* smem, int k,
                                            int wave, int lane) {
  int c = k % 7;
  unsigned short* dst = smem + ((k & 1) << 15);
  const unsigned short* src = wsW + c * 32768;
#pragma unroll
  for (int rr = 0; rr < 8; ++rr) {
    int f = rr * 8 + wave;
    gload_lds16(src + f * 512 + lane * 8, dst + f * 512 + lane * 8);
  }
  if (wave == 0 && c == 0) {
    int t = 31 - k / 7;
    if (t >= 0) {
      float* biasF = (float*)(smem + 73728);
      gload_lds16(b1eff + t * 256 + lane * 4, biasF + lane * 4);
    }
  }
}

#define MF(W, B, C) __builtin_amdgcn_mfma_f32_16x16x32_bf16((W), (B), (C), 0, 0, 0)

// ---------- main persistent kernel ----------
__global__ __launch_bounds__(512, 2) void diff_main(
    const float* __restrict__ cond, const float* __restrict__ x_init,
    const float* __restrict__ b2g, const float* __restrict__ b3g, const float* __restrict__ b4g,
    const unsigned short* __restrict__ wsW, const float* __restrict__ b1eff,
    float* __restrict__ out, Consts C) {
  extern __shared__ unsigned short smem[];
  unsigned short* scratch = smem + 65536;          // byte 131072: 8 waves x 2 KB
  float* biasF = (float*)(smem + 73728);           // byte 147456: [b1eff_t 256][b2 256][b3 256][b4 64]

  const int tid = threadIdx.x;
  const int wave = tid >> 6, lane = tid & 63;
  const int l15 = lane & 15, l4 = lane >> 4;
  const int lane8 = lane * 8;
  const int row = blockIdx.x * BM + wave * 16 + l15;   // this lane's row r

  // stage b2/b3/b4 -> LDS
  for (int i = tid; i < 576; i += 512) {
    float v = (i < 256) ? b2g[i] : (i < 512) ? b3g[i - 256] : b4g[i - 512];
    biasF[256 + i] = v;
  }

  // x master (f32) in C-fragment layout: x[tt][j] = x[r=row][c=16tt+4*l4+j]
  float x[4][4];
#pragma unroll
  for (int tt = 0; tt < 4; ++tt) {
    float4 xv = *(const float4*)(x_init + (size_t)row * 64 + 16 * tt + 4 * l4);
    x[tt][0] = xv.x; x[tt][1] = xv.y; x[tt][2] = xv.z; x[tt][3] = xv.w;
  }

  // cond B-frags, register-resident: cf[T] = cond[r=row][k=32T+8*l4+e]
  bf16x8 cf[8];
#pragma unroll
  for (int T = 0; T < 8; ++T) {
    const float* p = cond + (size_t)row * 256 + 32 * T + 8 * l4;
    float4 a = *(const float4*)p;
    float4 b = *(const float4*)(p + 4);
    union { bf16x8 v; unsigned u[4]; } cu;
    cu.u[0] = cvtpk(a.x, a.y); cu.u[1] = cvtpk(a.z, a.w);
    cu.u[2] = cvtpk(b.x, b.y); cu.u[3] = cvtpk(b.z, b.w);
    cf[T] = cu.v;
  }

  // wave-private scratch transpose: acc layout -> B-frags (16 r x 32 k, XOR slot swizzle)
  unsigned short* scr0 = scratch + wave * 1024;
  bf16x8 xf[2];
#define XTRANS() do { \
  _Pragma("unroll") for (int T_ = 0; T_ < 2; ++T_) { \
    unsigned short* scrT = scr0 + (T_ & 1) * 512; \
    _Pragma("unroll") for (int p_ = 0; p_ < 2; ++p_) { \
      int tt_ = 2 * T_ + p_; \
      uint2 wv_; wv_.x = cvtpk(x[tt_][0], x[tt_][1]); wv_.y = cvtpk(x[tt_][2], x[tt_][3]); \
      *(uint2*)(scrT + l15 * 32 + (((p_ << 2) | l4) ^ (l15 & 6)) * 4) = wv_; \
    } \
    xf[T_] = *(const bf16x8*)(scrT + l15 * 32 + (((l4 << 1) ^ (l15 & 6)) * 4)); \
  } \
} while (0)

  XTRANS();

  int ck = 0;
  const unsigned short* bufp = smem;
  issue_chunk(wsW, b1eff, smem, 0, wave, lane);
  __syncthreads();                                   // chunk0 (+b1eff[31]) resident
  issue_chunk(wsW, b1eff, smem, 1, wave, lane);

  f32x4 acc[16];
  const f32x4 zero4 = {0.f, 0.f, 0.f, 0.f};
  bf16x8 hf[8];

#define WFRAG(f) (*(const bf16x8*)(bufp + (f) * 512 + lane8))
#define SEG16(FBASE, HFR) { bf16x8 b_ = (HFR); \
  _Pragma("unroll") for (int tt_ = 0; tt_ < 16; ++tt_) \
    acc[tt_] = MF(WFRAG((FBASE) + tt_), b_, acc[tt_]); }
#define SEG4(FBASE, HFR) { bf16x8 b_ = (HFR); \
  _Pragma("unroll") for (int tt_ = 0; tt_ < 4; ++tt_) \
    acc[tt_] = MF(WFRAG((FBASE) + tt_), b_, acc[tt_]); }
#define NEXTCHUNK() do { __syncthreads(); ++ck; bufp = smem + ((ck & 1) << 15); \
  issue_chunk(wsW, b1eff, smem, ck + 1, wave, lane); } while (0)
#define ACT(BOFF) do { \
  _Pragma("unroll") for (int T_ = 0; T_ < 8; ++T_) { \
    unsigned short* scrT = scr0 + (T_ & 1) * 512; \
    _Pragma("unroll") for (int p_ = 0; p_ < 2; ++p_) { \
      int tt_ = 2 * T_ + p_; \
      float4 bv = *(const float4*)(biasF + (BOFF) + tt_ * 16 + l4 * 4); \
      float s0 = silu(acc[tt_][0] + bv.x), s1 = silu(acc[tt_][1] + bv.y); \
      float s2 = silu(acc[tt_][2] + bv.z), s3 = silu(acc[tt_][3] + bv.w); \
      uint2 wv_; wv_.x = cvtpk(s0, s1); wv_.y = cvtpk(s2, s3); \
      *(uint2*)(scrT + l15 * 32 + (((p_ << 2) | l4) ^ (l15 & 6)) * 4) = wv_; \
    } \
    hf[T_] = *(const bf16x8*)(scrT + l15 * 32 + (((l4 << 1) ^ (l15 & 6)) * 4)); \
  } \
} while (0)
#define ZACC(N) { _Pragma("unroll") for (int z_ = 0; z_ < (N); ++z_) acc[z_] = zero4; }

#pragma unroll 1
  for (int t = 31; t >= 0; --t) {
    ZACC(16);
    // chunk0: L1x T0,T1 + L1c T0,T1
    SEG16(0, xf[0]); SEG16(16, xf[1]); SEG16(32, cf[0]); SEG16(48, cf[1]);
    NEXTCHUNK();
    // chunk1: L1c T2..T5
    SEG16(0, cf[2]); SEG16(16, cf[3]); SEG16(32, cf[4]); SEG16(48, cf[5]);
    NEXTCHUNK();
    // chunk2: L1c T6,T7 ; h1 = silu(acc + b1eff) ; L2 T0,T1
    SEG16(0, cf[6]); SEG16(16, cf[7]);
    ACT(0);
    ZACC(16);
    SEG16(32, hf[0]); SEG16(48, hf[1]);
    NEXTCHUNK();
    // chunk3: L2 T2..T5
    SEG16(0, hf[2]); SEG16(16, hf[3]); SEG16(32, hf[4]); SEG16(48, hf[5]);
    NEXTCHUNK();
    // chunk4: L2 T6,T7 ; h2 ; L3 T0,T1
    SEG16(0, hf[6]); SEG16(16, hf[7]);
    ACT(256);
    ZACC(16);
    SEG16(32, hf[0]); SEG16(48, hf[1]);
    NEXTCHUNK();
    // chunk5: L3 T2..T5
    SEG16(0, hf[2]); SEG16(16, hf[3]); SEG16(32, hf[4]); SEG16(48, hf[5]);
    NEXTCHUNK();
    // chunk6: L3 T6,T7 ; h3 ; L4 ; diffusion update
    SEG16(0, hf[6]); SEG16(16, hf[7]);
    ACT(512);
    ZACC(4);
#pragma unroll
    for (int T = 0; T < 8; ++T) SEG4(32 + 4 * T, hf[T]);

    float sqab = C.sqab[t], s1d = C.s1d[t], sqa = C.sqa[t], sqb = C.sqb[t], inva = C.inva[t];
    (void)sqab;
    unsigned kk0 = C.k0[31 - t], kk1 = C.k1[31 - t];
#pragma unroll
    for (int tt = 0; tt < 4; ++tt) {
      float4 b4v = *(const float4*)(biasF + 768 + tt * 16 + l4 * 4);
#pragma unroll
      for (int j = 0; j < 4; ++j) {
        float bj = (j == 0) ? b4v.x : (j == 1) ? b4v.y : (j == 2) ? b4v.z : b4v.w;
        float eps = acc[tt][j] + bj;
        float x0p = fmaf(-s1d, eps, x[tt][j]) * inva;
        if (t > 0) {
          float z = noise_normal(kk0, kk1, (unsigned)(row * 64 + 16 * tt + 4 * l4 + j));
          x[tt][j] = sqa * x0p + sqb * z;
        } else {
          x[tt][j] = x0p;
        }
      }
    }
    if (t > 0) {
      XTRANS();          // new x_t -> B-frags for next step's L1
    } else {
#pragma unroll
      for (int tt = 0; tt < 4; ++tt) {
        float4 ov; ov.x = x[tt][0]; ov.y = x[tt][1]; ov.z = x[tt][2]; ov.w = x[tt][3];
        *(float4*)(out + (size_t)row * 64 + 16 * tt + 4 * l4) = ov;
      }
    }
    NEXTCHUNK();
  }
}

// ---------- host ----------
static void host_threefry(unsigned k0, unsigned k1, unsigned x0, unsigned x1,
                          unsigned* o0, unsigned* o1) {
  unsigned ks2 = k0 ^ k1 ^ 0x1BD11BDAu;
  x0 += k0; x1 += k1;
#define HR(r) { x0 += x1; x1 = (x1 << r) | (x1 >> (32 - r)); x1 ^= x0; }
  HR(13) HR(15) HR(26) HR(6)
  x0 += k1;  x1 += ks2 + 1u;
  HR(17) HR(29) HR(16) HR(24)
  x0 += ks2; x1 += k0 + 2u;
  HR(13) HR(15) HR(26) HR(6)
  x0 += k0;  x1 += k1 + 3u;
  HR(17) HR(29) HR(16) HR(24)
  x0 += k1;  x1 += ks2 + 4u;
  HR(13) HR(15) HR(26) HR(6)
  x0 += ks2; x1 += k0 + 5u;
#undef HR
  *o0 = x0; *o1 = x1;
}

extern "C" void kernel_launch(void* const* d_in, const int* in_sizes, int n_in,
                              void* d_out, int out_size, void* d_ws, size_t ws_size,
                              hipStream_t stream) {
  const float* cond   = (const float*)d_in[0];
  const float* x_init = (const float*)d_in[1];
  const float* W1 = (const float*)d_in[2];
  const float* b1 = (const float*)d_in[3];
  const float* W2 = (const float*)d_in[4];
  const float* b2 = (const float*)d_in[5];
  const float* W3 = (const float*)d_in[6];
  const float* b3 = (const float*)d_in[7];
  const float* W4 = (const float*)d_in[8];
  const float* b4 = (const float*)d_in[9];

  unsigned short* wbuf = (unsigned short*)d_ws;          // 448 KB frag-major weights
  float* b1eff = (float*)((char*)d_ws + 458752);         // 32 KB

  pack_w_k<<<896, 256, 0, stream>>>(W1, W2, W3, W4, wbuf);
  b1eff_k<<<32, 256, 0, stream>>>(W1, b1, b1eff);

  Consts C;
  // jax.random.split(jax.random.key(42), 32), threefry_partitionable (verified r2)
  for (int i = 0; i < 32; ++i) {
    unsigned o0, o1;
    host_threefry(0u, 42u, 0u, (unsigned)i, &o0, &o1);
    C.k0[i] = o0; C.k1[i] = o1;
  }
  // schedule constants — identical f32 op sequence to the (passing) r3 device code
  {
    const float bstep = (0.01f - 0.0001f) / 31.0f;
    float abar = 1.0f;
    for (int t = 0; t < 32; ++t) {
      float beta_t = 0.0001f + bstep * (float)t;
      float alpha_t = 1.0f - beta_t;
      abar *= (1.0f - (0.0001f + bstep * (float)t));
      C.sqab[t] = sqrtf(abar);
      C.s1d[t]  = sqrtf(1.0f - abar);
      C.sqa[t]  = sqrtf(alpha_t);
      C.sqb[t]  = sqrtf(beta_t);
      C.inva[t] = 1.0f / sqrtf(abar);
    }
  }

  const int shmem = 150784;   // 2x64KB weight dbuf + 16KB scratch + 2.3KB biases
  hipFuncSetAttribute((const void*)diff_main, hipFuncAttributeMaxDynamicSharedMemorySize, 160 * 1024);
  diff_main<<<NBLK, 512, shmem, stream>>>(cond, x_init, b2, b3, b4,
                                          wbuf, b1eff, (float*)d_out, C);
}